// Round 1
// baseline (166.978 us; speedup 1.0000x reference)
//
#include <hip/hip_runtime.h>
#include <hip/hip_bf16.h>
#include <stdint.h>

#define T_TOKENS 8192
#define D_DIM 1024
#define H_DIM 2048
#define N_EXPERTS 8

typedef __attribute__((ext_vector_type(8))) short bf16x8;
typedef __attribute__((ext_vector_type(4))) float f32x4;

typedef __attribute__((address_space(1))) const void* gptr_t;
typedef __attribute__((address_space(3))) void* lptr_t;

__device__ __forceinline__ unsigned short f2bf(float f) {
  union { float f; unsigned int u; } x; x.f = f;
  unsigned int r = x.u + 0x7FFFu + ((x.u >> 16) & 1u);
  return (unsigned short)(r >> 16);
}
__device__ __forceinline__ float bf2f(unsigned short b) {
  union { unsigned int u; float f; } x; x.u = ((unsigned int)b) << 16;
  return x.f;
}

__global__ void cvt_f32_bf16_kernel(const float* __restrict__ in,
                                    unsigned short* __restrict__ out, int n) {
  int tid = blockIdx.x * blockDim.x + threadIdx.x;
  int stride = gridDim.x * blockDim.x;
  for (int i = tid * 4; i < n; i += stride * 4) {
    const float4 v = *reinterpret_cast<const float4*>(in + i);
    ushort4 o;
    o.x = f2bf(v.x); o.y = f2bf(v.y); o.z = f2bf(v.z); o.w = f2bf(v.w);
    *reinterpret_cast<ushort4*>(out + i) = o;
  }
}

__device__ __forceinline__ void gload_lds16(const void* g, void* l) {
  __builtin_amdgcn_global_load_lds((gptr_t)g, (lptr_t)l, 16, 0, 0);
}

// C[M,N] = A[M,K] @ B[e][N,K]^T over expert row-segments (rows sorted by expert).
// FUSE=true: out = bf16(relu(bf16(acc))^2) -> outB.  FUSE=false: out = float(bf16(acc)) -> outF.
template <int K, int N, bool FUSE>
__global__ void grouped_gemm_bt(const unsigned short* __restrict__ A,
                                const unsigned short* __restrict__ B,
                                const int* __restrict__ counts,
                                unsigned short* __restrict__ outB,
                                float* __restrict__ outF) {
  __shared__ short lA[128 * 64];
  __shared__ short lB[128 * 64];

  const int tid = threadIdx.x;
  const int wid = tid >> 6;
  const int lane = tid & 63;
  const int r0 = blockIdx.y * 128;
  const int c0 = blockIdx.x * 128;

  int csum[N_EXPERTS + 1];
  csum[0] = 0;
  for (int e = 0; e < N_EXPERTS; ++e) csum[e + 1] = csum[e] + counts[e];
  int eLo = 0;
  while (eLo < N_EXPERTS - 1 && csum[eLo + 1] <= r0) ++eLo;
  int eHi = eLo;
  while (eHi < N_EXPERTS - 1 && csum[eHi + 1] < r0 + 128) ++eHi;

  const int lrow = lane >> 3;          // 0..7   (row within 8-row group)
  const int lcolb = (lane & 7) * 8;    // 0..56  (bf16 element col)
  const int wr = wid >> 1, wc = wid & 1;

  for (int e = eLo; e <= eHi; ++e) {
    const unsigned short* Be = B + (size_t)e * N * K;
    f32x4 acc[4][4];
#pragma unroll
    for (int mi = 0; mi < 4; ++mi)
#pragma unroll
      for (int ni = 0; ni < 4; ++ni)
        acc[mi][ni] = (f32x4){0.f, 0.f, 0.f, 0.f};

    for (int kt = 0; kt < K / 64; ++kt) {
      // Stage A tile [128][64] and B tile [128][64] into LDS.
      // Each global_load_lds: 64 lanes * 16B = 8 rows of 128B, LDS-linear.
#pragma unroll
      for (int j = 0; j < 4; ++j) {
        const int rb = wid * 32 + j * 8;
        gload_lds16(A + (size_t)(r0 + rb + lrow) * K + kt * 64 + lcolb, &lA[rb * 64]);
        gload_lds16(Be + (size_t)(c0 + rb + lrow) * K + kt * 64 + lcolb, &lB[rb * 64]);
      }
      __syncthreads();  // compiler drains vmcnt before s_barrier
#pragma unroll
      for (int kk = 0; kk < 2; ++kk) {
        bf16x8 af[4], bfr[4];
#pragma unroll
        for (int mi = 0; mi < 4; ++mi)
          af[mi] = *(const bf16x8*)&lA[(wr * 64 + mi * 16 + (lane & 15)) * 64 + kk * 32 + (lane >> 4) * 8];
#pragma unroll
        for (int ni = 0; ni < 4; ++ni)
          bfr[ni] = *(const bf16x8*)&lB[(wc * 64 + ni * 16 + (lane & 15)) * 64 + kk * 32 + (lane >> 4) * 8];
#pragma unroll
        for (int mi = 0; mi < 4; ++mi)
#pragma unroll
          for (int ni = 0; ni < 4; ++ni)
            acc[mi][ni] = __builtin_amdgcn_mfma_f32_16x16x32_bf16(af[mi], bfr[ni], acc[mi][ni], 0, 0, 0);
      }
      __syncthreads();
    }

    // Epilogue: C/D layout col=lane&15, row=(lane>>4)*4+reg (m89/m91 verified).
    const int segLo = csum[e], segHi = csum[e + 1];
#pragma unroll
    for (int mi = 0; mi < 4; ++mi) {
      const int rowb = r0 + wr * 64 + mi * 16 + ((lane >> 4) << 2);
#pragma unroll
      for (int ni = 0; ni < 4; ++ni) {
        const int col = c0 + wc * 64 + ni * 16 + (lane & 15);
#pragma unroll
        for (int r = 0; r < 4; ++r) {
          const int gr = rowb + r;
          if (gr >= segLo && gr < segHi) {
            float y = acc[mi][ni][r];
            if (FUSE) {
              float h = bf2f(f2bf(y));   // bf16 round (matches ref)
              h = h > 0.f ? h : 0.f;     // relu
              outB[(size_t)gr * N + col] = f2bf(h * h);  // bf16 square
            } else {
              outF[(size_t)gr * N + col] = bf2f(f2bf(y));  // bf16 round, fp32 store
            }
          }
        }
      }
    }
  }
}

extern "C" void kernel_launch(void* const* d_in, const int* in_sizes, int n_in,
                              void* d_out, int out_size, void* d_ws, size_t ws_size,
                              hipStream_t stream) {
  const float* x = (const float*)d_in[0];       // (T, D) fp32
  const float* w_up = (const float*)d_in[1];    // (E, H, D) fp32
  const float* w_down = (const float*)d_in[2];  // (E, D, H) fp32
  const int* counts = (const int*)d_in[3];      // (E,) int32
  float* out = (float*)d_out;                   // (T, D) fp32

  char* ws = (char*)d_ws;
  unsigned short* xb  = (unsigned short*)(ws);                            // 16 MB
  unsigned short* wub = (unsigned short*)(ws + (size_t)16 * 1024 * 1024); // 32 MB
  unsigned short* wdb = (unsigned short*)(ws + (size_t)48 * 1024 * 1024); // 32 MB
  unsigned short* hsq = (unsigned short*)(ws + (size_t)80 * 1024 * 1024); // 32 MB

  cvt_f32_bf16_kernel<<<2048, 256, 0, stream>>>(x, xb, T_TOKENS * D_DIM);
  cvt_f32_bf16_kernel<<<2048, 256, 0, stream>>>(w_up, wub, N_EXPERTS * H_DIM * D_DIM);
  cvt_f32_bf16_kernel<<<2048, 256, 0, stream>>>(w_down, wdb, N_EXPERTS * D_DIM * H_DIM);

  // GEMM1: hsq = relu(bf16(x @ w_up^T))^2  -> (T, H) bf16
  grouped_gemm_bt<D_DIM, H_DIM, true>
      <<<dim3(H_DIM / 128, T_TOKENS / 128), 256, 0, stream>>>(xb, wub, counts, hsq, nullptr);
  // GEMM2: out = float(bf16(hsq @ w_down^T)) -> (T, D) fp32
  grouped_gemm_bt<H_DIM, D_DIM, false>
      <<<dim3(D_DIM / 128, T_TOKENS / 128), 256, 0, stream>>>(hsq, wdb, counts, nullptr, out);
}

// Round 2
// 164.472 us; speedup vs baseline: 1.0152x; 1.0152x over previous
//
#include <hip/hip_runtime.h>
#include <hip/hip_bf16.h>
#include <stdint.h>

#define T_TOKENS 8192
#define D_DIM 1024
#define H_DIM 2048
#define N_EXPERTS 8

typedef __attribute__((ext_vector_type(8))) short bf16x8;
typedef __attribute__((ext_vector_type(4))) float f32x4;

typedef __attribute__((address_space(1))) const void* gptr_t;
typedef __attribute__((address_space(3))) void* lptr_t;

__device__ __forceinline__ unsigned short f2bf(float f) {
  union { float f; unsigned int u; } x; x.f = f;
  unsigned int r = x.u + 0x7FFFu + ((x.u >> 16) & 1u);
  return (unsigned short)(r >> 16);
}
__device__ __forceinline__ float bf2f(unsigned short b) {
  union { unsigned int u; float f; } x; x.u = ((unsigned int)b) << 16;
  return x.f;
}

__device__ __forceinline__ void gload16(const void* g, void* l) {
  __builtin_amdgcn_global_load_lds((gptr_t)g, (lptr_t)l, 16, 0, 0);
}

// Sync discipline (rule #18: sched_barrier after inline-asm waits / raw barriers)
#define SBAR()  do { __builtin_amdgcn_s_barrier(); __builtin_amdgcn_sched_barrier(0); } while (0)
#define LGKM0() do { asm volatile("s_waitcnt lgkmcnt(0)" ::: "memory"); __builtin_amdgcn_sched_barrier(0); } while (0)
#define VMW(n)  do { __builtin_amdgcn_sched_barrier(0); asm volatile("s_waitcnt vmcnt(" #n ")" ::: "memory"); } while (0)

// ---------------------------------------------------------------------------
// Fused fp32 -> bf16 conversion of x, w_up, w_down (one kernel, BW-bound).
// ---------------------------------------------------------------------------
__global__ void cvt_all(const float* __restrict__ x, const float* __restrict__ wu,
                        const float* __restrict__ wd,
                        unsigned short* __restrict__ xb, unsigned short* __restrict__ wub,
                        unsigned short* __restrict__ wdb) {
  const int NX = T_TOKENS * D_DIM / 4;
  const int NW = N_EXPERTS * H_DIM * D_DIM / 4;
  const int total = NX + 2 * NW;
  for (int i = blockIdx.x * blockDim.x + threadIdx.x; i < total; i += gridDim.x * blockDim.x) {
    const float* src; unsigned short* dst; int off;
    if (i < NX)            { src = x;  dst = xb;  off = i; }
    else if (i < NX + NW)  { src = wu; dst = wub; off = i - NX; }
    else                   { src = wd; dst = wdb; off = i - NX - NW; }
    const float4 v = *reinterpret_cast<const float4*>(src + (size_t)off * 4);
    ushort4 o;
    o.x = f2bf(v.x); o.y = f2bf(v.y); o.z = f2bf(v.z); o.w = f2bf(v.w);
    *reinterpret_cast<ushort4*>(dst + (size_t)off * 4) = o;
  }
}

// ---------------------------------------------------------------------------
// GEMM1: hsq[T,H] = bf16(relu(bf16(x @ w_up^T))^2), grouped by expert rows.
// BM=256 BN=256 BK=64. 8 waves 2Mx4N (per-wave 128x64). 4 phases/K-tile
// (m-half x K-half). LDS: 4 K-half slots per operand, [256][32] bf16 each.
// Counted vmcnt(8) at phases 2 and 4; one s_barrier per phase.
// ---------------------------------------------------------------------------
__global__ __launch_bounds__(512, 2)
void gg1_up(const unsigned short* __restrict__ A,  // (T, D) bf16
            const unsigned short* __restrict__ B,  // (E, H, D) bf16
            const int* __restrict__ counts,
            unsigned short* __restrict__ O) {      // (T, H) bf16
  constexpr int K = D_DIM;
  constexpr int NT = K / 64;  // 16
  __shared__ short lA[4 * 8192];  // 4 slots x [256][32]
  __shared__ short lB[4 * 8192];

  const int tid = threadIdx.x;
  const int wid = tid >> 6, lane = tid & 63;
  const int wr = wid >> 2, wc = wid & 3;
  const int bid = blockIdx.x;
  const int cb = bid & 7, rb = bid >> 3;  // T1: XCD k owns column panel k
  const int r0 = rb * 256, c0 = cb * 256;

  int csum[N_EXPERTS + 1];
  csum[0] = 0;
  for (int e = 0; e < N_EXPERTS; ++e) csum[e + 1] = csum[e] + counts[e];
  int eLo = 0;
  while (eLo < N_EXPERTS - 1 && csum[eLo + 1] <= r0) ++eLo;
  int eHi = eLo;
  while (eHi < N_EXPERTS - 1 && csum[eHi + 1] < r0 + 256) ++eHi;

  // staging: per wave-line 16 rows x 64B; lane -> row (lane>>2), col (lane&3)*8
  const int srow = lane >> 2;
  const int scol = (lane & 3) * 8;
  const size_t aBase = (size_t)(r0 + wid * 16 + srow) * K + scol;
  const size_t bBase0 = (size_t)(c0 + wid * 16 + srow) * K + scol;
  const int ldsW = wid * 512;
  const int l15 = lane & 15, l4 = (lane >> 4) * 8;

  for (int e = eLo; e <= eHi; ++e) {
    const unsigned short* Be = B + (size_t)e * H_DIM * K;
    f32x4 acc[8][4];
#pragma unroll
    for (int mi = 0; mi < 8; ++mi)
#pragma unroll
      for (int ni = 0; ni < 4; ++ni) acc[mi][ni] = (f32x4){0.f, 0.f, 0.f, 0.f};

#define STAGE_A1(t, h) do { const int s_ = (((t) & 1) << 1) | (h); \
    gload16(A + aBase + (size_t)(t) * 64 + (h) * 32,                 &lA[s_ * 8192 + ldsW]); \
    gload16(A + aBase + (size_t)128 * K + (size_t)(t) * 64 + (h) * 32, &lA[s_ * 8192 + ldsW + 4096]); } while (0)
#define STAGE_B1(t, h) do { const int s_ = (((t) & 1) << 1) | (h); \
    gload16(Be + bBase0 + (size_t)(t) * 64 + (h) * 32,                 &lB[s_ * 8192 + ldsW]); \
    gload16(Be + bBase0 + (size_t)128 * K + (size_t)(t) * 64 + (h) * 32, &lB[s_ * 8192 + ldsW + 4096]); } while (0)
#define G1_RD(MH, SLOT) do { \
    _Pragma("unroll") for (int m_ = 0; m_ < 4; ++m_) \
      fa[m_] = *(const bf16x8*)&lA[(SLOT) * 8192 + (wr * 128 + (MH) * 64 + m_ * 16 + l15) * 32 + l4]; \
    _Pragma("unroll") for (int n_ = 0; n_ < 4; ++n_) \
      fb[n_] = *(const bf16x8*)&lB[(SLOT) * 8192 + (wc * 64 + n_ * 16 + l15) * 32 + l4]; \
  } while (0)
#define G1_MM(MH) do { \
    __builtin_amdgcn_s_setprio(1); \
    _Pragma("unroll") for (int m_ = 0; m_ < 4; ++m_) \
      _Pragma("unroll") for (int n_ = 0; n_ < 4; ++n_) \
        acc[(MH) * 4 + m_][n_] = __builtin_amdgcn_mfma_f32_16x16x32_bf16(fa[m_], fb[n_], acc[(MH) * 4 + m_][n_], 0, 0, 0); \
    __builtin_amdgcn_s_setprio(0); \
  } while (0)

    // prologue: tile0 complete + tile1 K-half0
    STAGE_A1(0, 0); STAGE_B1(0, 0); STAGE_A1(0, 1); STAGE_B1(0, 1);
    STAGE_A1(1, 0); STAGE_B1(1, 0);
    VMW(8); SBAR();

#pragma unroll 1
    for (int t = 0; t < NT - 2; ++t) {
      const int k0 = ((t & 1) << 1), k1 = k0 | 1;
      { bf16x8 fa[4], fb[4]; G1_RD(0, k0); STAGE_A1(t + 1, 1);          LGKM0(); G1_MM(0); SBAR(); }
      { bf16x8 fa[4], fb[4]; G1_RD(1, k0); STAGE_B1(t + 1, 1); VMW(8);  LGKM0(); G1_MM(1); SBAR(); }
      { bf16x8 fa[4], fb[4]; G1_RD(0, k1); STAGE_A1(t + 2, 0);          LGKM0(); G1_MM(0); SBAR(); }
      { bf16x8 fa[4], fb[4]; G1_RD(1, k1); STAGE_B1(t + 2, 0); VMW(8);  LGKM0(); G1_MM(1); SBAR(); }
    }
    {  // t = NT-2
      const int k0 = (((NT - 2) & 1) << 1), k1 = k0 | 1;
      { bf16x8 fa[4], fb[4]; G1_RD(0, k0); STAGE_A1(NT - 1, 1);         LGKM0(); G1_MM(0); SBAR(); }
      { bf16x8 fa[4], fb[4]; G1_RD(1, k0); STAGE_B1(NT - 1, 1); VMW(8); LGKM0(); G1_MM(1); SBAR(); }
      { bf16x8 fa[4], fb[4]; G1_RD(0, k1);                              LGKM0(); G1_MM(0); SBAR(); }
      { bf16x8 fa[4], fb[4]; G1_RD(1, k1);                     VMW(4);  LGKM0(); G1_MM(1); SBAR(); }
    }
    {  // t = NT-1
      const int k0 = (((NT - 1) & 1) << 1), k1 = k0 | 1;
      { bf16x8 fa[4], fb[4]; G1_RD(0, k0);                              LGKM0(); G1_MM(0); SBAR(); }
      { bf16x8 fa[4], fb[4]; G1_RD(1, k0);                     VMW(0);  LGKM0(); G1_MM(1); SBAR(); }
      { bf16x8 fa[4], fb[4]; G1_RD(0, k1);                              LGKM0(); G1_MM(0); SBAR(); }
      { bf16x8 fa[4], fb[4]; G1_RD(1, k1);                              LGKM0(); G1_MM(1); SBAR(); }
    }

    // epilogue: C/D layout col=lane&15, row=(lane>>4)*4+reg
    const int segLo = csum[e], segHi = csum[e + 1];
#pragma unroll
    for (int mi = 0; mi < 8; ++mi) {
      const int rowb = r0 + wr * 128 + mi * 16 + ((lane >> 4) << 2);
#pragma unroll
      for (int ni = 0; ni < 4; ++ni) {
        const int col = c0 + wc * 64 + ni * 16 + l15;
#pragma unroll
        for (int r = 0; r < 4; ++r) {
          const int gr = rowb + r;
          if (gr >= segLo && gr < segHi) {
            float h = bf2f(f2bf(acc[mi][ni][r]));
            h = h > 0.f ? h : 0.f;
            O[(size_t)gr * H_DIM + col] = f2bf(h * h);
          }
        }
      }
    }
#undef STAGE_A1
#undef STAGE_B1
#undef G1_RD
#undef G1_MM
  }
}

// ---------------------------------------------------------------------------
// GEMM2: out[T,D] = fp32(bf16(hsq @ w_down^T)), grouped.
// BM=256 BN=128 BK=64. 8 waves 4Mx2N (per-wave 64x64). 2 phases/K-tile (K-half).
// Counted vmcnt(6) at every phase.
// ---------------------------------------------------------------------------
__global__ __launch_bounds__(512, 2)
void gg2_down(const unsigned short* __restrict__ A,  // (T, H) bf16
              const unsigned short* __restrict__ B,  // (E, D, H) bf16
              const int* __restrict__ counts,
              float* __restrict__ O) {               // (T, D) fp32
  constexpr int K = H_DIM;
  constexpr int NT = K / 64;  // 32
  __shared__ short lA[4 * 8192];  // 4 slots x [256][32]
  __shared__ short lB[4 * 4096];  // 4 slots x [128][32]

  const int tid = threadIdx.x;
  const int wid = tid >> 6, lane = tid & 63;
  const int wr = wid >> 1, wc = wid & 1;
  const int bid = blockIdx.x;
  const int cb = bid & 7, rb = bid >> 3;
  const int r0 = rb * 256, c0 = cb * 128;

  int csum[N_EXPERTS + 1];
  csum[0] = 0;
  for (int e = 0; e < N_EXPERTS; ++e) csum[e + 1] = csum[e] + counts[e];
  int eLo = 0;
  while (eLo < N_EXPERTS - 1 && csum[eLo + 1] <= r0) ++eLo;
  int eHi = eLo;
  while (eHi < N_EXPERTS - 1 && csum[eHi + 1] < r0 + 256) ++eHi;

  const int srow = lane >> 2;
  const int scol = (lane & 3) * 8;
  const size_t aBase = (size_t)(r0 + wid * 16 + srow) * K + scol;
  const size_t bBase0 = (size_t)(c0 + wid * 16 + srow) * K + scol;
  const int ldsW = wid * 512;
  const int l15 = lane & 15, l4 = (lane >> 4) * 8;

  for (int e = eLo; e <= eHi; ++e) {
    const unsigned short* Be = B + (size_t)e * D_DIM * K;
    f32x4 acc[4][4];
#pragma unroll
    for (int mi = 0; mi < 4; ++mi)
#pragma unroll
      for (int ni = 0; ni < 4; ++ni) acc[mi][ni] = (f32x4){0.f, 0.f, 0.f, 0.f};

#define STAGE_A2(t, h) do { const int s_ = (((t) & 1) << 1) | (h); \
    gload16(A + aBase + (size_t)(t) * 64 + (h) * 32,                 &lA[s_ * 8192 + ldsW]); \
    gload16(A + aBase + (size_t)128 * K + (size_t)(t) * 64 + (h) * 32, &lA[s_ * 8192 + ldsW + 4096]); } while (0)
#define STAGE_B2(t, h) do { const int s_ = (((t) & 1) << 1) | (h); \
    gload16(Be + bBase0 + (size_t)(t) * 64 + (h) * 32, &lB[s_ * 4096 + ldsW]); } while (0)
#define G2_RD(SLOT) do { \
    _Pragma("unroll") for (int m_ = 0; m_ < 4; ++m_) \
      fa[m_] = *(const bf16x8*)&lA[(SLOT) * 8192 + (wr * 64 + m_ * 16 + l15) * 32 + l4]; \
    _Pragma("unroll") for (int n_ = 0; n_ < 4; ++n_) \
      fb[n_] = *(const bf16x8*)&lB[(SLOT) * 4096 + (wc * 64 + n_ * 16 + l15) * 32 + l4]; \
  } while (0)
#define G2_MM() do { \
    __builtin_amdgcn_s_setprio(1); \
    _Pragma("unroll") for (int m_ = 0; m_ < 4; ++m_) \
      _Pragma("unroll") for (int n_ = 0; n_ < 4; ++n_) \
        acc[m_][n_] = __builtin_amdgcn_mfma_f32_16x16x32_bf16(fa[m_], fb[n_], acc[m_][n_], 0, 0, 0); \
    __builtin_amdgcn_s_setprio(0); \
  } while (0)

    STAGE_A2(0, 0); STAGE_B2(0, 0); STAGE_A2(0, 1); STAGE_B2(0, 1);
    STAGE_A2(1, 0); STAGE_B2(1, 0);
    VMW(6); SBAR();

#pragma unroll 1
    for (int t = 0; t < NT - 2; ++t) {
      const int k0 = ((t & 1) << 1), k1 = k0 | 1;
      { bf16x8 fa[4], fb[4]; G2_RD(k0); STAGE_A2(t + 1, 1); STAGE_B2(t + 1, 1); VMW(6); LGKM0(); G2_MM(); SBAR(); }
      { bf16x8 fa[4], fb[4]; G2_RD(k1); STAGE_A2(t + 2, 0); STAGE_B2(t + 2, 0); VMW(6); LGKM0(); G2_MM(); SBAR(); }
    }
    {  // t = NT-2
      const int k0 = (((NT - 2) & 1) << 1), k1 = k0 | 1;
      { bf16x8 fa[4], fb[4]; G2_RD(k0); STAGE_A2(NT - 1, 1); STAGE_B2(NT - 1, 1); VMW(6); LGKM0(); G2_MM(); SBAR(); }
      { bf16x8 fa[4], fb[4]; G2_RD(k1);                                          VMW(3); LGKM0(); G2_MM(); SBAR(); }
    }
    {  // t = NT-1
      const int k0 = (((NT - 1) & 1) << 1), k1 = k0 | 1;
      { bf16x8 fa[4], fb[4]; G2_RD(k0);                                          VMW(0); LGKM0(); G2_MM(); SBAR(); }
      { bf16x8 fa[4], fb[4]; G2_RD(k1);                                                  LGKM0(); G2_MM(); SBAR(); }
    }

    const int segLo = csum[e], segHi = csum[e + 1];
#pragma unroll
    for (int mi = 0; mi < 4; ++mi) {
      const int rowb = r0 + wr * 64 + mi * 16 + ((lane >> 4) << 2);
#pragma unroll
      for (int ni = 0; ni < 4; ++ni) {
        const int col = c0 + wc * 64 + ni * 16 + l15;
#pragma unroll
        for (int r = 0; r < 4; ++r) {
          const int gr = rowb + r;
          if (gr >= segLo && gr < segHi) {
            O[(size_t)gr * D_DIM + col] = bf2f(f2bf(acc[mi][ni][r]));
          }
        }
      }
    }
#undef STAGE_A2
#undef STAGE_B2
#undef G2_RD
#undef G2_MM
  }
}

extern "C" void kernel_launch(void* const* d_in, const int* in_sizes, int n_in,
                              void* d_out, int out_size, void* d_ws, size_t ws_size,
                              hipStream_t stream) {
  const float* x = (const float*)d_in[0];
  const float* w_up = (const float*)d_in[1];
  const float* w_down = (const float*)d_in[2];
  const int* counts = (const int*)d_in[3];
  float* out = (float*)d_out;

  char* ws = (char*)d_ws;
  unsigned short* xb  = (unsigned short*)(ws);
  unsigned short* wub = (unsigned short*)(ws + (size_t)16 * 1024 * 1024);
  unsigned short* wdb = (unsigned short*)(ws + (size_t)48 * 1024 * 1024);
  unsigned short* hsq = (unsigned short*)(ws + (size_t)80 * 1024 * 1024);

  cvt_all<<<2048, 256, 0, stream>>>(x, w_up, w_down, xb, wub, wdb);
  gg1_up<<<256, 512, 0, stream>>>(xb, wub, counts, hsq);
  gg2_down<<<256, 512, 0, stream>>>(hsq, wdb, counts, out);
}